// Round 12
// baseline (354.444 us; speedup 1.0000x reference)
//
#include <hip/hip_runtime.h>
#include <math.h>

typedef _Float16 f16_t;
typedef _Float16 f16x8 __attribute__((ext_vector_type(8)));
typedef _Float16 f16x4 __attribute__((ext_vector_type(4)));
typedef _Float16 f16x2 __attribute__((ext_vector_type(2)));
typedef __fp16 h16x2 __attribute__((ext_vector_type(2)));
typedef float f32x4 __attribute__((ext_vector_type(4)));

#define LDS_BYTES 71680

// fp32 -> fp16 weights in 16x16x32-MFMA A-fragment-linear order:
// element (kc, nt, lane, j) = W[nt*16 + (lane&15)][kc*32 + (lane>>4)*8 + j]
// at ((kc*16 + nt)*64 + lane)*8 + j.  W1 kc0..3 at 0; W2 kc0..7 at 32768.
__global__ void wconv(const float* __restrict__ W1, const float* __restrict__ W2,
                      f16_t* __restrict__ o) {
  int i = blockIdx.x * 256 + threadIdx.x;  // 0..65535
  if (i < 32768) {
    int n = i >> 7, k = i & 127;
    int kc = k >> 5, q = (k >> 3) & 3, j = k & 7;
    int nt = n >> 4, c = n & 15;
    o[((kc * 16 + nt) * 64 + q * 16 + c) * 8 + j] = (f16_t)W1[i];
  }
  {
    int n = i >> 8, k = i & 255;
    int kc = k >> 5, q = (k >> 3) & 3, j = k & 7;
    int nt = n >> 4, c = n & 15;
    o[32768 + ((kc * 16 + nt) * 64 + q * 16 + c) * 8 + j] = (f16_t)W2[i];
  }
}

// h fp32 -> fp16
__global__ void hconv(const float* __restrict__ h, f16_t* __restrict__ hf, int n8) {
  int i = blockIdx.x * 256 + threadIdx.x;
  if (i < n8) {
    const float4 a = *(const float4*)(h + i * 8);
    const float4 b = *(const float4*)(h + i * 8 + 4);
    f16x8 v;
    v[0] = (f16_t)a.x; v[1] = (f16_t)a.y; v[2] = (f16_t)a.z; v[3] = (f16_t)a.w;
    v[4] = (f16_t)b.x; v[5] = (f16_t)b.y; v[6] = (f16_t)b.z; v[7] = (f16_t)b.w;
    *(f16x8*)(hf + i * 8) = v;
  }
}

__device__ __forceinline__ f16x2 pk2(float a, float b) {
  union { h16x2 h; f16x2 f; } u;
  u.h = __builtin_amdgcn_cvt_pkrtz(a, b);
  return u.f;
}

// Two-subtile software-pipelined fused MLP: D[feat][edge] = W @ x^T.
// Block = 128 edges as two 64-edge subtiles A/B; 512 threads, 8 waves =
// 4 feat-rows (64f) x 2 edge-cols (32e). acc[4][2] = 32 AGPR per live GEMM;
// staggered liveness keeps peak at 64 AGPR (v8-proven no-spill).
// Phases interleave tile-B MFMA with tile-A LN (different HW pipes overlap
// inside one wave's stream). Weights stream global(L2)->VGPR frag-linear.
// LDS: xA 32KB | xB 32KB | statsA 2KB | statsB 2KB | pA/pB 2KB = 70KB dynamic.
__global__ __launch_bounds__(512) void fused_mlp(
    const float* __restrict__ h,
    const f16_t* __restrict__ hf, int use_hf,
    const int* __restrict__ src,
    const int* __restrict__ dst,
    const f16_t* __restrict__ wks,
    const float* __restrict__ b1, const float* __restrict__ g1, const float* __restrict__ be1,
    const float* __restrict__ b2, const float* __restrict__ g2, const float* __restrict__ be2,
    const float* __restrict__ w3, const float* __restrict__ b3,
    float* __restrict__ out, int E, int nrows) {
  extern __shared__ __attribute__((aligned(16))) char smem[];
  f16_t* xA = (f16_t*)smem;                 // x0A [64][128] in low 16KB; x1A [64][256]
  f16_t* xB = (f16_t*)(smem + 32768);
  float* sAsum = (float*)(smem + 65536);    // [4][64]
  float* sAsq  = (float*)(smem + 65536) + 256;
  float* sBsum = (float*)(smem + 67584);
  float* sBsq  = (float*)(smem + 67584) + 256;
  float* pA    = (float*)(smem + 69632);    // [4][64]
  float* pB    = (float*)(smem + 70656);

  const int t = threadIdx.x;
  const int ebase = blockIdx.x * 128;

  // ---------- P1: gather both subtiles ----------
  {
    const int m = t >> 3;   // local edge 0..63
    const int j = t & 7;    // 16-f16 slice
    const int g0 = ((j * 2) ^ m) & 15;
    const int g1i = ((j * 2 + 1) ^ m) & 15;
#pragma unroll
    for (int tb = 0; tb < 2; ++tb) {
      f16_t* xT = tb ? xB : xA;
      const int e = ebase + tb * 64 + m;
      f16_t* xrow = xT + m * 128;
      if (e < E) {
        int si = src[e], di = dst[e];
        si = ((unsigned)si < (unsigned)nrows) ? si : 0;
        di = ((unsigned)di < (unsigned)nrows) ? di : 0;
        if (use_hf) {
          const f16_t* hs = hf + (long long)si * 128 + j * 16;
          const f16_t* hd = hf + (long long)di * 128 + j * 16;
          f16x8 a0 = *(const f16x8*)(hs);
          f16x8 a1 = *(const f16x8*)(hs + 8);
          f16x8 c0 = *(const f16x8*)(hd);
          f16x8 c1 = *(const f16x8*)(hd + 8);
          *(f16x8*)(xrow + g0 * 8) = a0 * c0;
          *(f16x8*)(xrow + g1i * 8) = a1 * c1;
        } else {
          const float* hs = h + (long long)si * 128 + j * 16;
          const float* hd = h + (long long)di * 128 + j * 16;
          const float4 a0 = *(const float4*)(hs);
          const float4 a1 = *(const float4*)(hs + 4);
          const float4 a2 = *(const float4*)(hs + 8);
          const float4 a3 = *(const float4*)(hs + 12);
          const float4 c0 = *(const float4*)(hd);
          const float4 c1 = *(const float4*)(hd + 4);
          const float4 c2 = *(const float4*)(hd + 8);
          const float4 c3 = *(const float4*)(hd + 12);
          union { f16x8 v8; f16x2 v2[4]; } u0, u1;
          u0.v2[0] = pk2(a0.x * c0.x, a0.y * c0.y);
          u0.v2[1] = pk2(a0.z * c0.z, a0.w * c0.w);
          u0.v2[2] = pk2(a1.x * c1.x, a1.y * c1.y);
          u0.v2[3] = pk2(a1.z * c1.z, a1.w * c1.w);
          u1.v2[0] = pk2(a2.x * c2.x, a2.y * c2.y);
          u1.v2[1] = pk2(a2.z * c2.z, a2.w * c2.w);
          u1.v2[2] = pk2(a3.x * c3.x, a3.y * c3.y);
          u1.v2[3] = pk2(a3.z * c3.z, a3.w * c3.w);
          *(f16x8*)(xrow + g0 * 8) = u0.v8;
          *(f16x8*)(xrow + g1i * 8) = u1.v8;
        }
      } else {
        f16x8 z = {};
        *(f16x8*)(xrow + g0 * 8) = z;
        *(f16x8*)(xrow + g1i * 8) = z;
      }
    }
  }
  __syncthreads();  // s1: x0A, x0B ready

  const int lane = t & 63;
  const int wave = t >> 6;
  const int wf = wave & 3;   // feat-row (64 feats)
  const int ec = wave >> 2;  // edge-col (32 edges)
  const int c = lane & 15;
  const int q = lane >> 4;
  const int featBase = wf * 64;
  int el[2];
  el[0] = ec * 32 + c;       // local edge, n=0
  el[1] = el[0] + 16;        // n=1
  const f16_t* wb1 = wks + wf * 2048 + lane * 8;
  const f16_t* wb2 = wks + 32768 + wf * 2048 + lane * 8;

  auto gemm1 = [&](const f16_t* xT, f32x4 (&A)[4][2]) {
#pragma unroll
    for (int kc = 0; kc < 4; ++kc) {
      f16x8 af[4], bf[2];
#pragma unroll
      for (int msf = 0; msf < 4; ++msf)
        af[msf] = *(const f16x8*)(wb1 + kc * 8192 + msf * 512);
      const int gp = ((kc * 4 + q) ^ c) & 15;
      bf[0] = *(const f16x8*)(xT + el[0] * 128 + gp * 8);
      bf[1] = *(const f16x8*)(xT + el[1] * 128 + gp * 8);
#pragma unroll
      for (int msf = 0; msf < 4; ++msf)
#pragma unroll
        for (int n = 0; n < 2; ++n)
          A[msf][n] = __builtin_amdgcn_mfma_f32_16x16x32_f16(af[msf], bf[n], A[msf][n], 0, 0, 0);
    }
  };
  auto gemm2 = [&](const f16_t* xT, f32x4 (&A)[4][2]) {
#pragma unroll
    for (int kc = 0; kc < 8; ++kc) {
      f16x8 af[4], bf[2];
#pragma unroll
      for (int msf = 0; msf < 4; ++msf)
        af[msf] = *(const f16x8*)(wb2 + kc * 8192 + msf * 512);
      const int g = kc * 4 + q;
      const int gp = (g & 16) | ((g ^ c) & 15);
      bf[0] = *(const f16x8*)(xT + el[0] * 256 + gp * 8);
      bf[1] = *(const f16x8*)(xT + el[1] * 256 + gp * 8);
#pragma unroll
      for (int msf = 0; msf < 4; ++msf)
#pragma unroll
        for (int n = 0; n < 2; ++n)
          A[msf][n] = __builtin_amdgcn_mfma_f32_16x16x32_f16(af[msf], bf[n], A[msf][n], 0, 0, 0);
    }
  };
  // stats: bias-add into acc, per-edge sum/sumsq -> partials
  auto lnstats = [&](f32x4 (&A)[4][2], const float* bias, float* ssum, float* ssq) {
#pragma unroll
    for (int n = 0; n < 2; ++n) {
      f32x4 s4 = (f32x4){0.f, 0.f, 0.f, 0.f}, q4 = s4;
#pragma unroll
      for (int msf = 0; msf < 4; ++msf) {
        const f32x4 bv = *(const f32x4*)(bias + featBase + msf * 16 + q * 4);
        f32x4 v = A[msf][n] + bv;
        A[msf][n] = v;
        s4 += v;
        q4 += v * v;
      }
      float s = s4[0] + s4[1] + s4[2] + s4[3];
      float sq = q4[0] + q4[1] + q4[2] + q4[3];
      s += __shfl_xor(s, 16, 64);  s += __shfl_xor(s, 32, 64);
      sq += __shfl_xor(sq, 16, 64); sq += __shfl_xor(sq, 32, 64);
      if (q == 0) {
        ssum[wf * 64 + el[n]] = s;
        ssq[wf * 64 + el[n]] = sq;
      }
    }
  };
  auto lnmean = [&](const float* ssum, const float* ssq, float (&mu)[2], float (&rs)[2]) {
#pragma unroll
    for (int n = 0; n < 2; ++n) {
      const int e = el[n];
      float s = ssum[e] + ssum[64 + e] + ssum[128 + e] + ssum[192 + e];
      float sq = ssq[e] + ssq[64 + e] + ssq[128 + e] + ssq[192 + e];
      mu[n] = s * (1.f / 256.f);
      rs[n] = rsqrtf(sq * (1.f / 256.f) - mu[n] * mu[n] + 1e-5f);
    }
  };
  // normalize + relu + fp16-pack + write x1 into xT (stride 256, swizzled)
  auto norm1w = [&](f32x4 (&A)[4][2], const float (&mu)[2], const float (&rs)[2],
                    f16_t* xT) {
    const f32x4 z4 = (f32x4){0.f, 0.f, 0.f, 0.f};
    const int j0 = (q & 1) * 4;
#pragma unroll
    for (int msf = 0; msf < 4; ++msf) {
      const f32x4 gv = *(const f32x4*)(g1 + featBase + msf * 16 + q * 4);
      const f32x4 bev = *(const f32x4*)(be1 + featBase + msf * 16 + q * 4);
      const int g = wf * 8 + msf * 2 + (q >> 1);
      const int gp = (g & 16) | ((g ^ c) & 15);
#pragma unroll
      for (int n = 0; n < 2; ++n) {
        f32x4 v = (A[msf][n] - mu[n]) * (gv * rs[n]) + bev;
        v = __builtin_elementwise_max(v, z4);
        union { f16x4 v4; f16x2 v2p[2]; } u;
        u.v2p[0] = pk2(v[0], v[1]); u.v2p[1] = pk2(v[2], v[3]);
        *(f16x4*)(xT + el[n] * 256 + gp * 8 + j0) = u.v4;
      }
    }
  };
  auto norm2dot = [&](f32x4 (&A)[4][2], const float (&mu)[2], const float (&rs)[2],
                      float* pT) {
    const f32x4 z4 = (f32x4){0.f, 0.f, 0.f, 0.f};
    f32x4 p4[2] = {z4, z4};
#pragma unroll
    for (int msf = 0; msf < 4; ++msf) {
      const f32x4 gv = *(const f32x4*)(g2 + featBase + msf * 16 + q * 4);
      const f32x4 bev = *(const f32x4*)(be2 + featBase + msf * 16 + q * 4);
      const f32x4 wv = *(const f32x4*)(w3 + featBase + msf * 16 + q * 4);
#pragma unroll
      for (int n = 0; n < 2; ++n) {
        f32x4 v = (A[msf][n] - mu[n]) * (gv * rs[n]) + bev;
        v = __builtin_elementwise_max(v, z4);
        p4[n] += v * wv;
      }
    }
#pragma unroll
    for (int n = 0; n < 2; ++n) {
      float p = p4[n][0] + p4[n][1] + p4[n][2] + p4[n][3];
      p += __shfl_xor(p, 16, 64);
      p += __shfl_xor(p, 32, 64);
      if (q == 0) pT[wf * 64 + el[n]] = p;
    }
  };

  f32x4 accA[4][2], accB[4][2], acc2A[4][2], acc2B[4][2];
  float mu[2], rs[2];

  // ---------- P2: GEMM1(A) + stats(A) ----------
#pragma unroll
  for (int msf = 0; msf < 4; ++msf)
#pragma unroll
    for (int n = 0; n < 2; ++n) accA[msf][n] = (f32x4){0.f, 0.f, 0.f, 0.f};
  gemm1(xA, accA);
  lnstats(accA, b1, sAsum, sAsq);
  __syncthreads();  // s2: statsA ready; x0A reads done

  // ---------- P3: GEMM1(B) overlapped with LN1(A) -> x1A ----------
#pragma unroll
  for (int msf = 0; msf < 4; ++msf)
#pragma unroll
    for (int n = 0; n < 2; ++n) accB[msf][n] = (f32x4){0.f, 0.f, 0.f, 0.f};
  gemm1(xB, accB);           // MFMA in flight
  lnmean(sAsum, sAsq, mu, rs);
  norm1w(accA, mu, rs, xA);  // VALU + x1A writes under MFMA shadow
  lnstats(accB, b1, sBsum, sBsq);
  __syncthreads();  // s3: x1A visible; statsB ready; x0B reads done

  // ---------- P4: GEMM2(A) overlapped with LN1(B) -> x1B ----------
#pragma unroll
  for (int msf = 0; msf < 4; ++msf)
#pragma unroll
    for (int n = 0; n < 2; ++n) acc2A[msf][n] = (f32x4){0.f, 0.f, 0.f, 0.f};
  gemm2(xA, acc2A);
  lnmean(sBsum, sBsq, mu, rs);
  norm1w(accB, mu, rs, xB);
  lnstats(acc2A, b2, sAsum, sAsq);  // statsA region free since s3
  __syncthreads();  // s4: x1B visible; LN2statsA ready; x1A reads done

  // ---------- P5: GEMM2(B) overlapped with LN2(A) -> pA ----------
#pragma unroll
  for (int msf = 0; msf < 4; ++msf)
#pragma unroll
    for (int n = 0; n < 2; ++n) acc2B[msf][n] = (f32x4){0.f, 0.f, 0.f, 0.f};
  gemm2(xB, acc2B);
  lnmean(sAsum, sAsq, mu, rs);
  norm2dot(acc2A, mu, rs, pA);
  lnstats(acc2B, b2, sBsum, sBsq);
  __syncthreads();  // s5: pA ready; LN2statsB ready

  // ---------- P6: out(A) + LN2(B) -> pB ----------
  if (t < 64) {
    int e = ebase + t;
    if (e < E) {
      float sres = pA[t] + pA[64 + t] + pA[128 + t] + pA[192 + t] + b3[0];
      out[e] = 1.f / (1.f + __expf(-sres));
    }
  }
  lnmean(sBsum, sBsq, mu, rs);
  norm2dot(acc2B, mu, rs, pB);
  __syncthreads();  // s6: pB ready
  if (t < 64) {
    int e = ebase + 64 + t;
    if (e < E) {
      float sres = pB[t] + pB[64 + t] + pB[128 + t] + pB[192 + t] + b3[0];
      out[e] = 1.f / (1.f + __expf(-sres));
    }
  }
}

extern "C" void kernel_launch(void* const* d_in, const int* in_sizes, int n_in,
                              void* d_out, int out_size, void* d_ws, size_t ws_size,
                              hipStream_t stream) {
  const float* h = (const float*)d_in[0];
  const int* src = (const int*)d_in[1];
  const int* dst = (const int*)d_in[2];
  const float* W1 = (const float*)d_in[3];
  const float* b1 = (const float*)d_in[4];
  const float* g1 = (const float*)d_in[5];
  const float* be1 = (const float*)d_in[6];
  const float* W2 = (const float*)d_in[7];
  const float* b2 = (const float*)d_in[8];
  const float* g2 = (const float*)d_in[9];
  const float* be2 = (const float*)d_in[10];
  const float* W3 = (const float*)d_in[11];
  const float* b3 = (const float*)d_in[12];
  float* out = (float*)d_out;
  const int E = in_sizes[1];
  const int nh = in_sizes[0];
  const int nrows = nh / 128;
  f16_t* wks = (f16_t*)d_ws;   // 196608 B weights
  f16_t* hfp = wks + 98304;    // fp16 h mirror
  const size_t need = 196608 + (size_t)nh * 2;
  const int use_hf = (ws_size >= need) ? 1 : 0;

  wconv<<<256, 256, 0, stream>>>(W1, W2, wks);
  if (use_hf) {
    const int n8 = nh / 8;
    hconv<<<(n8 + 255) / 256, 256, 0, stream>>>(h, hfp, n8);
  }
  (void)hipFuncSetAttribute((const void*)fused_mlp,
                            hipFuncAttributeMaxDynamicSharedMemorySize, LDS_BYTES);
  const int tiles = (E + 127) / 128;
  fused_mlp<<<tiles, 512, LDS_BYTES, stream>>>(h, hfp, use_hf, src, dst, wks,
                                               b1, g1, be1, b2, g2, be2, W3, b3,
                                               out, E, nrows);
}

// Round 13
// 302.015 us; speedup vs baseline: 1.1736x; 1.1736x over previous
//
#include <hip/hip_runtime.h>
#include <math.h>

typedef _Float16 f16_t;
typedef _Float16 f16x8 __attribute__((ext_vector_type(8)));
typedef _Float16 f16x4 __attribute__((ext_vector_type(4)));
typedef _Float16 f16x2 __attribute__((ext_vector_type(2)));
typedef __fp16 h16x2 __attribute__((ext_vector_type(2)));
typedef float f32x4 __attribute__((ext_vector_type(4)));

// fp32 -> fp16 weights in 16x16x32-MFMA A-fragment-linear order:
// element (kc, nt, lane, j) = W[nt*16 + (lane&15)][kc*32 + (lane>>4)*8 + j]
// at ((kc*16 + nt)*64 + lane)*8 + j.  W1 kc0..3 at 0; W2 kc0..7 at 32768.
__global__ void wconv(const float* __restrict__ W1, const float* __restrict__ W2,
                      f16_t* __restrict__ o) {
  int i = blockIdx.x * 256 + threadIdx.x;  // 0..65535
  if (i < 32768) {
    int n = i >> 7, k = i & 127;
    int kc = k >> 5, q = (k >> 3) & 3, j = k & 7;
    int nt = n >> 4, c = n & 15;
    o[((kc * 16 + nt) * 64 + q * 16 + c) * 8 + j] = (f16_t)W1[i];
  }
  {
    int n = i >> 8, k = i & 255;
    int kc = k >> 5, q = (k >> 3) & 3, j = k & 7;
    int nt = n >> 4, c = n & 15;
    o[32768 + ((kc * 16 + nt) * 64 + q * 16 + c) * 8 + j] = (f16_t)W2[i];
  }
}

// h fp32 -> fp16
__global__ void hconv(const float* __restrict__ h, f16_t* __restrict__ hf, int n8) {
  int i = blockIdx.x * 256 + threadIdx.x;
  if (i < n8) {
    const float4 a = *(const float4*)(h + i * 8);
    const float4 b = *(const float4*)(h + i * 8 + 4);
    f16x8 v;
    v[0] = (f16_t)a.x; v[1] = (f16_t)a.y; v[2] = (f16_t)a.z; v[3] = (f16_t)a.w;
    v[4] = (f16_t)b.x; v[5] = (f16_t)b.y; v[6] = (f16_t)b.z; v[7] = (f16_t)b.w;
    *(f16x8*)(hf + i * 8) = v;
  }
}

__device__ __forceinline__ f16x2 pk2(float a, float b) {
  union { h16x2 h; f16x2 f; } u;
  u.h = __builtin_amdgcn_cvt_pkrtz(a, b);
  return u.f;
}

// Transposed fused MLP: D[feat][edge] = W @ x^T. Tile = 64 edges, 512 threads,
// 8 waves = 4 feat-rows (64f) x 2 edge-cols (32e); acc[4][2] = 32 AGPR + ~52 VGPR
// (the v8-measured no-spill footprint -> 6 waves/SIMD fits). Weights stream
// global(L2)->VGPR fragment-linear (zero staging barriers). Bias pre-loaded into
// the accumulator init (no bias adds). Dedicated stats LDS -> only 5 barriers.
// LDS padded to exactly 48 KB so the HW cap is 3 blocks/CU (24 waves): the
// allocator's occupancy target becomes 85 regs, protecting our 84-reg footprint.
__global__ __launch_bounds__(512) void fused_mlp(
    const float* __restrict__ h,
    const f16_t* __restrict__ hf, int use_hf,
    const int* __restrict__ src,
    const int* __restrict__ dst,
    const f16_t* __restrict__ wks,
    const float* __restrict__ b1, const float* __restrict__ g1, const float* __restrict__ be1,
    const float* __restrict__ b2, const float* __restrict__ g2, const float* __restrict__ be2,
    const float* __restrict__ w3, const float* __restrict__ b3,
    float* __restrict__ out, int E, int nrows) {
  // 23040 f16 = 46080 B (x-buffer uses first 16384) + 3072 B stats = 49152 B total.
  __shared__ __attribute__((aligned(16))) f16_t xbuf[23040];
  __shared__ float ssum[256];   // [4 wf][64 e]
  __shared__ float ssq[256];
  __shared__ float pbuf[256];

  const int t = threadIdx.x;
  const int ebase = blockIdx.x * 64;

  // keep the padding region live (never executes: E > 0 always)
  if (E < 0) ((volatile f16_t*)xbuf)[16384 + t] = (f16_t)0.f;

  // ---------- gather: x0[m][k] = h[src][k]*h[dst][k], fp16, swizzled stride-128 ----------
  {
    const int m = t >> 3;   // edge 0..63
    const int j = t & 7;    // 16-f16 slice
    const int e = ebase + m;
    f16_t* xrow = xbuf + m * 128;
    const int g0 = ((j * 2) ^ m) & 15;
    const int g1i = ((j * 2 + 1) ^ m) & 15;
    if (e < E) {
      int si = src[e], di = dst[e];
      si = ((unsigned)si < (unsigned)nrows) ? si : 0;
      di = ((unsigned)di < (unsigned)nrows) ? di : 0;
      if (use_hf) {
        const f16_t* hs = hf + (long long)si * 128 + j * 16;
        const f16_t* hd = hf + (long long)di * 128 + j * 16;
        f16x8 a0 = *(const f16x8*)(hs);
        f16x8 a1 = *(const f16x8*)(hs + 8);
        f16x8 c0 = *(const f16x8*)(hd);
        f16x8 c1 = *(const f16x8*)(hd + 8);
        *(f16x8*)(xrow + g0 * 8) = a0 * c0;
        *(f16x8*)(xrow + g1i * 8) = a1 * c1;
      } else {
        const float* hs = h + (long long)si * 128 + j * 16;
        const float* hd = h + (long long)di * 128 + j * 16;
        const float4 a0 = *(const float4*)(hs);
        const float4 a1 = *(const float4*)(hs + 4);
        const float4 a2 = *(const float4*)(hs + 8);
        const float4 a3 = *(const float4*)(hs + 12);
        const float4 c0 = *(const float4*)(hd);
        const float4 c1 = *(const float4*)(hd + 4);
        const float4 c2 = *(const float4*)(hd + 8);
        const float4 c3 = *(const float4*)(hd + 12);
        union { f16x8 v8; f16x2 v2[4]; } u0, u1;
        u0.v2[0] = pk2(a0.x * c0.x, a0.y * c0.y);
        u0.v2[1] = pk2(a0.z * c0.z, a0.w * c0.w);
        u0.v2[2] = pk2(a1.x * c1.x, a1.y * c1.y);
        u0.v2[3] = pk2(a1.z * c1.z, a1.w * c1.w);
        u1.v2[0] = pk2(a2.x * c2.x, a2.y * c2.y);
        u1.v2[1] = pk2(a2.z * c2.z, a2.w * c2.w);
        u1.v2[2] = pk2(a3.x * c3.x, a3.y * c3.y);
        u1.v2[3] = pk2(a3.z * c3.z, a3.w * c3.w);
        *(f16x8*)(xrow + g0 * 8) = u0.v8;
        *(f16x8*)(xrow + g1i * 8) = u1.v8;
      }
    } else {
      f16x8 z = {};
      *(f16x8*)(xrow + g0 * 8) = z;
      *(f16x8*)(xrow + g1i * 8) = z;
    }
  }
  __syncthreads();  // b1: x0 ready

  const int lane = t & 63;
  const int wave = t >> 6;
  const int wf = wave >> 1;  // feat-row 0..3 (64 feats)
  const int we = wave & 1;   // edge-col 0..1 (32 edges)
  const int c = lane & 15;
  const int q = lane >> 4;
  const int featBase = wf * 64;
  int el[2];
  el[0] = we * 32 + c;
  el[1] = el[0] + 16;
  const f16_t* wb1 = wks + wf * 2048 + lane * 8;
  const f16_t* wb2 = wks + 32768 + wf * 2048 + lane * 8;

  // ---------- GEMM1: K=128, acc initialized to bias ----------
  f32x4 acc[4][2];
#pragma unroll
  for (int msf = 0; msf < 4; ++msf) {
    const f32x4 bv = *(const f32x4*)(b1 + featBase + msf * 16 + q * 4);
    acc[msf][0] = bv;
    acc[msf][1] = bv;
  }
#pragma unroll
  for (int kc = 0; kc < 4; ++kc) {
    f16x8 af[4], bf[2];
#pragma unroll
    for (int msf = 0; msf < 4; ++msf)
      af[msf] = *(const f16x8*)(wb1 + kc * 8192 + msf * 512);
    const int gp = ((kc * 4 + q) ^ c) & 15;
    bf[0] = *(const f16x8*)(xbuf + el[0] * 128 + gp * 8);
    bf[1] = *(const f16x8*)(xbuf + el[1] * 128 + gp * 8);
#pragma unroll
    for (int msf = 0; msf < 4; ++msf)
#pragma unroll
      for (int n = 0; n < 2; ++n)
        acc[msf][n] = __builtin_amdgcn_mfma_f32_16x16x32_f16(af[msf], bf[n], acc[msf][n], 0, 0, 0);
  }

  // ---------- LN1 stats ----------
  {
#pragma unroll
    for (int n = 0; n < 2; ++n) {
      f32x4 s4 = (f32x4){0.f, 0.f, 0.f, 0.f}, q4 = s4;
#pragma unroll
      for (int msf = 0; msf < 4; ++msf) {
        const f32x4 v = acc[msf][n];
        s4 += v;
        q4 += v * v;
      }
      float s = s4[0] + s4[1] + s4[2] + s4[3];
      float sq = q4[0] + q4[1] + q4[2] + q4[3];
      s += __shfl_xor(s, 16, 64);  s += __shfl_xor(s, 32, 64);
      sq += __shfl_xor(sq, 16, 64); sq += __shfl_xor(sq, 32, 64);
      if (q == 0) {
        ssum[wf * 64 + el[n]] = s;
        ssq[wf * 64 + el[n]] = sq;
      }
    }
  }
  __syncthreads();  // b2: stats ready; all x0 reads done

  float mu[2], rs[2];
#pragma unroll
  for (int n = 0; n < 2; ++n) {
    const int e = el[n];
    float s = ssum[e] + ssum[64 + e] + ssum[128 + e] + ssum[192 + e];
    float sq = ssq[e] + ssq[64 + e] + ssq[128 + e] + ssq[192 + e];
    mu[n] = s * (1.f / 256.f);
    rs[n] = rsqrtf(sq * (1.f / 256.f) - mu[n] * mu[n] + 1e-5f);
  }

  // ---------- LN1 normalize + ReLU -> x1 [64][256] (overwrites x0; x0 dead) ----------
  {
    const f32x4 z4 = (f32x4){0.f, 0.f, 0.f, 0.f};
    const int j0 = (q & 1) * 4;
#pragma unroll
    for (int msf = 0; msf < 4; ++msf) {
      const f32x4 gv = *(const f32x4*)(g1 + featBase + msf * 16 + q * 4);
      const f32x4 bev = *(const f32x4*)(be1 + featBase + msf * 16 + q * 4);
      const int g = wf * 8 + msf * 2 + (q >> 1);
      const int gp = (g & 16) | ((g ^ c) & 15);
#pragma unroll
      for (int n = 0; n < 2; ++n) {
        f32x4 v = (acc[msf][n] - mu[n]) * (gv * rs[n]) + bev;
        v = __builtin_elementwise_max(v, z4);
        union { f16x4 v4; f16x2 v2p[2]; } u;
        u.v2p[0] = pk2(v[0], v[1]); u.v2p[1] = pk2(v[2], v[3]);
        *(f16x4*)(xbuf + el[n] * 256 + gp * 8 + j0) = u.v4;
      }
    }
  }
  __syncthreads();  // b3: x1 visible

  // ---------- GEMM2: K=256, acc2 initialized to bias ----------
  f32x4 acc2[4][2];
#pragma unroll
  for (int msf = 0; msf < 4; ++msf) {
    const f32x4 bv = *(const f32x4*)(b2 + featBase + msf * 16 + q * 4);
    acc2[msf][0] = bv;
    acc2[msf][1] = bv;
  }
#pragma unroll
  for (int kc = 0; kc < 8; ++kc) {
    f16x8 af[4], bf[2];
#pragma unroll
    for (int msf = 0; msf < 4; ++msf)
      af[msf] = *(const f16x8*)(wb2 + kc * 8192 + msf * 512);
    const int g = kc * 4 + q;
    const int gp = (g & 16) | ((g ^ c) & 15);
    bf[0] = *(const f16x8*)(xbuf + el[0] * 256 + gp * 8);
    bf[1] = *(const f16x8*)(xbuf + el[1] * 256 + gp * 8);
#pragma unroll
    for (int msf = 0; msf < 4; ++msf)
#pragma unroll
      for (int n = 0; n < 2; ++n)
        acc2[msf][n] = __builtin_amdgcn_mfma_f32_16x16x32_f16(af[msf], bf[n], acc2[msf][n], 0, 0, 0);
  }

  // ---------- LN2 stats (stats1 fully consumed before b3; safe to overwrite) ----------
  {
#pragma unroll
    for (int n = 0; n < 2; ++n) {
      f32x4 s4 = (f32x4){0.f, 0.f, 0.f, 0.f}, q4 = s4;
#pragma unroll
      for (int msf = 0; msf < 4; ++msf) {
        const f32x4 v = acc2[msf][n];
        s4 += v;
        q4 += v * v;
      }
      float s = s4[0] + s4[1] + s4[2] + s4[3];
      float sq = q4[0] + q4[1] + q4[2] + q4[3];
      s += __shfl_xor(s, 16, 64);  s += __shfl_xor(s, 32, 64);
      sq += __shfl_xor(sq, 16, 64); sq += __shfl_xor(sq, 32, 64);
      if (q == 0) {
        ssum[wf * 64 + el[n]] = s;
        ssq[wf * 64 + el[n]] = sq;
      }
    }
  }
  __syncthreads();  // b4: LN2 stats ready; x1 reads done

#pragma unroll
  for (int n = 0; n < 2; ++n) {
    const int e = el[n];
    float s = ssum[e] + ssum[64 + e] + ssum[128 + e] + ssum[192 + e];
    float sq = ssq[e] + ssq[64 + e] + ssq[128 + e] + ssq[192 + e];
    mu[n] = s * (1.f / 256.f);
    rs[n] = rsqrtf(sq * (1.f / 256.f) - mu[n] * mu[n] + 1e-5f);
  }

  // ---------- LN2 normalize + ReLU + dot(W3) -> pbuf ----------
  {
    const f32x4 z4 = (f32x4){0.f, 0.f, 0.f, 0.f};
    f32x4 p4[2] = {z4, z4};
#pragma unroll
    for (int msf = 0; msf < 4; ++msf) {
      const f32x4 gv = *(const f32x4*)(g2 + featBase + msf * 16 + q * 4);
      const f32x4 bev = *(const f32x4*)(be2 + featBase + msf * 16 + q * 4);
      const f32x4 wv = *(const f32x4*)(w3 + featBase + msf * 16 + q * 4);
#pragma unroll
      for (int n = 0; n < 2; ++n) {
        f32x4 v = (acc2[msf][n] - mu[n]) * (gv * rs[n]) + bev;
        v = __builtin_elementwise_max(v, z4);
        p4[n] += v * wv;
      }
    }
#pragma unroll
    for (int n = 0; n < 2; ++n) {
      float p = p4[n][0] + p4[n][1] + p4[n][2] + p4[n][3];
      p += __shfl_xor(p, 16, 64);
      p += __shfl_xor(p, 32, 64);
      if (q == 0) pbuf[wf * 64 + el[n]] = p;
    }
  }
  __syncthreads();  // b5: pbuf ready
  if (t < 64) {
    int e = ebase + t;
    if (e < E) {
      float sres = pbuf[t] + pbuf[64 + t] + pbuf[128 + t] + pbuf[192 + t] + b3[0];
      out[e] = 1.f / (1.f + __expf(-sres));
    }
  }
}

extern "C" void kernel_launch(void* const* d_in, const int* in_sizes, int n_in,
                              void* d_out, int out_size, void* d_ws, size_t ws_size,
                              hipStream_t stream) {
  const float* h = (const float*)d_in[0];
  const int* src = (const int*)d_in[1];
  const int* dst = (const int*)d_in[2];
  const float* W1 = (const float*)d_in[3];
  const float* b1 = (const float*)d_in[4];
  const float* g1 = (const float*)d_in[5];
  const float* be1 = (const float*)d_in[6];
  const float* W2 = (const float*)d_in[7];
  const float* b2 = (const float*)d_in[8];
  const float* g2 = (const float*)d_in[9];
  const float* be2 = (const float*)d_in[10];
  const float* W3 = (const float*)d_in[11];
  const float* b3 = (const float*)d_in[12];
  float* out = (float*)d_out;
  const int E = in_sizes[1];
  const int nh = in_sizes[0];
  const int nrows = nh / 128;
  f16_t* wks = (f16_t*)d_ws;   // 196608 B weights
  f16_t* hfp = wks + 98304;    // fp16 h mirror
  const size_t need = 196608 + (size_t)nh * 2;
  const int use_hf = (ws_size >= need) ? 1 : 0;

  wconv<<<256, 256, 0, stream>>>(W1, W2, wks);
  if (use_hf) {
    const int n8 = nh / 8;
    hconv<<<(n8 + 255) / 256, 256, 0, stream>>>(h, hfp, n8);
  }
  const int tiles = (E + 63) / 64;
  fused_mlp<<<tiles, 512, 0, stream>>>(h, hfp, use_hf, src, dst, wks,
                                       b1, g1, be1, b2, g2, be2, W3, b3,
                                       out, E, nrows);
}